// Round 14
// baseline (148.535 us; speedup 1.0000x reference)
//
#include <hip/hip_runtime.h>
#include <stdint.h>

#define NP 100000
#define MP 32
#define OC 64
#define NBLK 1563                 // ceil(NP/64): one 64-pillar group per block
#define BNEPS 0.001f
#define MTOT 3200000.0
#define GIDX(i,j) ((i)*10 - (i)*((i)-1)/2 + ((j)-(i)))   // 10x10 upper-tri, 55
#define BG(a,b) B[((a)<=(b)) ? ((a)*(7-(a))/2+(b)) : ((b)*(7-(b))/2+(a))]  // 4x4 upper-tri, 10

typedef float f2 __attribute__((ext_vector_type(2)));

// ---- 64-lane sum (DPP butterfly + swizzle + half exchange) ----
__device__ __forceinline__ float redall(float v) {
    v += __int_as_float(__builtin_amdgcn_update_dpp(0, __float_as_int(v), 0xB1,  0xF, 0xF, true));
    v += __int_as_float(__builtin_amdgcn_update_dpp(0, __float_as_int(v), 0x4E,  0xF, 0xF, true));
    v += __int_as_float(__builtin_amdgcn_update_dpp(0, __float_as_int(v), 0x141, 0xF, 0xF, true));
    v += __int_as_float(__builtin_amdgcn_update_dpp(0, __float_as_int(v), 0x140, 0xF, 0xF, true));
    v += __int_as_float(__builtin_amdgcn_ds_swizzle(__float_as_int(v), 0x401F));
    v += __shfl_xor(v, 32, 64);
    return v;
}

// ---------------------------------------------------------------------------
// Prep: folded weights. wptab[(c/2)*4+k] = f2{sgn*w2[k]}(ch c even/odd halves);
// btab[2c]={sgn*wcl[0..2], sgn*wce[0]}, btab[2c+1]={sgn*wce[1..2], sgn, 0}.
// ---------------------------------------------------------------------------
__global__ void sap_prep(const float* __restrict__ W, const float* __restrict__ gamma,
                         float* __restrict__ wptab, float4* __restrict__ btab)
{
    const int c = threadIdx.x;   // 64
    float w2[4], wcl[3], wce[3];
    w2[3] = W[3 * OC + c];
    #pragma unroll
    for (int k = 0; k < 3; ++k) {
        wcl[k] = W[(4 + k) * OC + c];
        wce[k] = W[(7 + k) * OC + c];
        w2[k]  = W[k * OC + c] + wcl[k] + wce[k];
    }
    const float sgn = (gamma[c] >= 0.0f) ? 1.0f : -1.0f;
    #pragma unroll
    for (int k = 0; k < 4; ++k)
        wptab[(((c >> 1) * 4) + k) * 2 + (c & 1)] = w2[k] * sgn;   // f2 halves
    btab[2*c]   = make_float4(wcl[0]*sgn, wcl[1]*sgn, wcl[2]*sgn, wce[0]*sgn);
    btab[2*c+1] = make_float4(wce[1]*sgn, wce[2]*sgn, sgn, 0.0f);
}

// ---------------------------------------------------------------------------
// Pass 1: LANE = PILLAR (r12 body). NO ATOMICS: wave 0 writes its block's 62
// partial stats to partials[block*64+lane] (coalesced, contention-free).
// ---------------------------------------------------------------------------
__global__ __launch_bounds__(256, 4) void sap_pass1(
    const float4* __restrict__ feat4, const int* __restrict__ nump,
    const int4* __restrict__ coors4, const f2* __restrict__ wptab,
    const float4* __restrict__ btab, float* __restrict__ hsel,
    float* __restrict__ partials)
{
    const int lane = threadIdx.x & 63;
    const int swid = __builtin_amdgcn_readfirstlane(threadIdx.x >> 6);
    const int n = blockIdx.x * 64 + lane;
    const bool valid = n < NP;
    const int nn = valid ? n : NP - 1;
    const int cnt = valid ? nump[nn] : 0;          // coalesced
    const int4 cr = coors4[nn];                    // coalesced 16B
    const float cenz = ((float)cr.y + 0.5f) * 0.2f;
    const float ceny = ((float)cr.z + 0.5f) * 0.2f;
    const float cenx = ((float)cr.w + 0.5f) * 4.0f;
    const float4* __restrict__ fp = feat4 + (size_t)nn * MP;

    // wave's 16 channels = 8 f2 pairs; uniform address -> scalar loads
    f2 wA[8], wB[8], wC[8], wD[8];
    #pragma unroll
    for (int j = 0; j < 8; ++j) {
        const int base = (swid * 8 + j) * 4;
        wA[j] = wptab[base];     wB[j] = wptab[base + 1];
        wC[j] = wptab[base + 2]; wD[j] = wptab[base + 3];
    }

    f2 mac[8];
    #pragma unroll
    for (int j = 0; j < 8; ++j) mac[j] = (f2){-3.0e38f, -3.0e38f};
    float S0 = 0.f, S1 = 0.f, S2 = 0.f, S3 = 0.f;
    float B[10];
    #pragma unroll
    for (int k = 0; k < 10; ++k) B[k] = 0.f;
    const bool doB = (swid == 0);

#define POINT(FF, P) {                                                          \
    const bool act = (P) < cnt;                                                 \
    const float neg = act ? 0.0f : -3.0e38f;                                    \
    const f2 neg2 = {neg, neg};                                                 \
    const f2 fx = {(FF).x, (FF).x}, fy = {(FF).y, (FF).y};                      \
    const f2 fz = {(FF).z, (FF).z}, fw = {(FF).w, (FF).w};                      \
    _Pragma("unroll")                                                           \
    for (int j = 0; j < 8; ++j) {                                               \
        const f2 d = __builtin_elementwise_fma(fx, wA[j],                       \
                     __builtin_elementwise_fma(fy, wB[j],                       \
                     __builtin_elementwise_fma(fz, wC[j],                       \
                     __builtin_elementwise_fma(fw, wD[j], neg2))));             \
        mac[j] = __builtin_elementwise_max(mac[j], d);                          \
    }                                                                           \
    const float ax = act ? (FF).x : 0.0f, ay = act ? (FF).y : 0.0f;             \
    const float az = act ? (FF).z : 0.0f;                                       \
    S0 += ax; S1 += ay; S2 += az;                                               \
    if (doB) {                                                                  \
        const float aw = act ? (FF).w : 0.0f;                                   \
        S3 += aw;                                                               \
        B[0]=fmaf(ax,ax,B[0]); B[1]=fmaf(ax,ay,B[1]); B[2]=fmaf(ax,az,B[2]);    \
        B[3]=fmaf(ax,aw,B[3]); B[4]=fmaf(ay,ay,B[4]); B[5]=fmaf(ay,az,B[5]);    \
        B[6]=fmaf(ay,aw,B[6]); B[7]=fmaf(az,az,B[7]); B[8]=fmaf(az,aw,B[8]);    \
        B[9]=fmaf(aw,aw,B[9]);                                                  \
    } }

    {
        float4 b0 = fp[0], b1 = fp[1], b2 = fp[2], b3 = fp[3];
        #pragma unroll 1
        for (int pq = 0; pq < 8; ++pq) {
            const int pb = pq * 4;
            float4 n0 = b0, n1 = b1, n2 = b2, n3 = b3;
            if (pq < 7) { n0 = fp[pb+4]; n1 = fp[pb+5]; n2 = fp[pb+6]; n3 = fp[pb+7]; }
            POINT(b0, pb + 0) POINT(b1, pb + 1)
            POINT(b2, pb + 2) POINT(b3, pb + 3)
            b0 = n0; b1 = n1; b2 = n2; b3 = n3;
        }
    }
#undef POINT

    // ---- epilogue: bias + floor + store (16 channels, 4x float4)
    const float fcnt = (float)cnt;
    const float rc = __builtin_amdgcn_rcpf(fmaxf(fcnt, 1.0f));
    const float mx = S0 * rc, my = S1 * rc, mz = S2 * rc;
    const float fl = (cnt < MP) ? 0.0f : -3.0e38f;
    #pragma unroll
    for (int q = 0; q < 4; ++q) {
        float o[4];
        #pragma unroll
        for (int k = 0; k < 4; ++k) {
            const int cc = q * 4 + k;
            const int c = swid * 16 + cc;
            const float4 bA = btab[2 * c];       // wcl0..2, wce0  (sgn-folded)
            const float4 bB = btab[2 * c + 1];   // wce1..2, sgn, 0
            const float bias = -(mx * bA.x + my * bA.y + mz * bA.z
                               + cenz * bA.w + ceny * bB.x + cenx * bB.y);
            const float m = (cc & 1) ? mac[cc >> 1].y : mac[cc >> 1].x;
            o[k] = bB.z * fmaxf(m + bias, fl);
        }
        if (valid)
            *reinterpret_cast<float4*>(hsel + (size_t)n * OC + swid * 16 + q * 4)
                = make_float4(o[0], o[1], o[2], o[3]);
    }

    // ---- wave 0: per-pillar Gram corrections -> 62 per-block partials
    if (doB) {
        float vals[62];
        const float Sf[4] = {S0, S1, S2, S3};
        const float mu[3] = {S0 * rc, S1 * rc, S2 * rc};
        const float ce[3] = {cenz, ceny, cenx};
        #pragma unroll
        for (int i = 0; i < 4; ++i)
            #pragma unroll
            for (int j = i; j < 4; ++j)
                vals[GIDX(i, j)] = BG(i, j);
        #pragma unroll
        for (int i = 0; i < 4; ++i)
            #pragma unroll
            for (int t = 0; t < 3; ++t)
                vals[GIDX(i, 4 + t)] = BG(i, t) - mu[t] * Sf[i];
        #pragma unroll
        for (int s = 0; s < 3; ++s)
            #pragma unroll
            for (int t = s; t < 3; ++t)
                vals[GIDX(4 + s, 4 + t)] = BG(s, t) - mu[s] * Sf[t];
        #pragma unroll
        for (int i = 0; i < 4; ++i)
            #pragma unroll
            for (int t = 0; t < 3; ++t)
                vals[GIDX(i, 7 + t)] = BG(i, t) - ce[t] * Sf[i];
        #pragma unroll
        for (int s = 0; s < 3; ++s)
            #pragma unroll
            for (int t = 0; t < 3; ++t)
                vals[GIDX(4 + s, 7 + t)] = BG(s, t) - mu[s] * Sf[t];
        #pragma unroll
        for (int s = 0; s < 3; ++s)
            #pragma unroll
            for (int t = s; t < 3; ++t)
                vals[GIDX(7 + s, 7 + t)] =
                    fmaf(fcnt * ce[s], ce[t], BG(s, t) - ce[s] * Sf[t] - ce[t] * Sf[s]);
        vals[55] = S0; vals[56] = S1; vals[57] = S2; vals[58] = S3;
        vals[59] = fmaf(-fcnt, cenz, S0);
        vals[60] = fmaf(-fcnt, ceny, S1);
        vals[61] = fmaf(-fcnt, cenx, S2);

        #pragma unroll
        for (int k = 0; k < 62; ++k) vals[k] = redall(vals[k]);
        float mine = 0.0f;
        #pragma unroll
        for (int k = 0; k < 62; ++k) mine = (lane == k) ? vals[k] : mine;
        if (lane < 62)
            partials[(size_t)blockIdx.x * 64 + lane] = mine;   // coalesced store
    }
}

// ---------------------------------------------------------------------------
// Reduce partials (fixed order = deterministic) + finalize BN -> scsh.
// ---------------------------------------------------------------------------
__global__ void sap_reduce_finalize(const float* __restrict__ partials,
                                    const float* __restrict__ W,
                                    const float* __restrict__ gamma,
                                    const float* __restrict__ beta,
                                    float* __restrict__ scsh)
{
    __shared__ float acc[4][64];
    __shared__ float stats[64];
    const int tid = threadIdx.x;          // 256
    const int k = tid & 63, q = tid >> 6;
    float s = 0.0f;
    for (int b = q; b < NBLK; b += 4) s += partials[(size_t)b * 64 + k];
    acc[q][k] = s;
    __syncthreads();
    if (tid < 64) stats[tid] = (acc[0][tid] + acc[1][tid]) + (acc[2][tid] + acc[3][tid]);
    __syncthreads();
    if (tid >= 64) return;
    const int c = tid;
    double G[55];
    #pragma unroll
    for (int kk = 0; kk < 55; ++kk) G[kk] = (double)stats[kk];
    double Sg[10];
    Sg[0] = (double)stats[55]; Sg[1] = (double)stats[56];
    Sg[2] = (double)stats[57]; Sg[3] = (double)stats[58];
    Sg[4] = 0.0; Sg[5] = 0.0; Sg[6] = 0.0;
    Sg[7] = (double)stats[59]; Sg[8] = (double)stats[60]; Sg[9] = (double)stats[61];
    double w[10];
    #pragma unroll
    for (int kk = 0; kk < 10; ++kk) w[kk] = (double)W[kk * OC + c];
    double sh = 0.0, qq = 0.0;
    #pragma unroll
    for (int kk = 0; kk < 10; ++kk) sh += Sg[kk] * w[kk];
    for (int i = 0; i < 10; ++i)
        for (int j = i; j < 10; ++j) {
            const double t = w[i] * w[j] * G[GIDX(i, j)];
            qq += (i == j) ? t : 2.0 * t;
        }
    const double mu_d = sh / MTOT;
    const double var_d = qq / MTOT - mu_d * mu_d;
    const float sc = gamma[c] * rsqrtf((float)var_d + BNEPS);
    scsh[c]      = sc;
    scsh[64 + c] = beta[c] - (float)mu_d * sc;
}

// ---------------------------------------------------------------------------
// Pass 2: in-place over d_out: out = relu(scale * hsel + shift).
// ---------------------------------------------------------------------------
__global__ __launch_bounds__(256) void sap_pass2(const float* __restrict__ scsh,
                                                 float* __restrict__ out)
{
    const int idx = blockIdx.x * 256 + threadIdx.x;
    if (idx >= (NP * OC) / 4) return;
    float4 h = reinterpret_cast<float4*>(out)[idx];
    const int ci = idx & 15;
    const float4 sc = reinterpret_cast<const float4*>(scsh)[ci];
    const float4 sh = reinterpret_cast<const float4*>(scsh + 64)[ci];
    float4 o;
    o.x = fmaxf(fmaf(h.x, sc.x, sh.x), 0.0f);
    o.y = fmaxf(fmaf(h.y, sc.y, sh.y), 0.0f);
    o.z = fmaxf(fmaf(h.z, sc.z, sh.z), 0.0f);
    o.w = fmaxf(fmaf(h.w, sc.w, sh.w), 0.0f);
    reinterpret_cast<float4*>(out)[idx] = o;
}

extern "C" void kernel_launch(void* const* d_in, const int* in_sizes, int n_in,
                              void* d_out, int out_size, void* d_ws, size_t ws_size,
                              hipStream_t stream) {
    const float* feat  = (const float*)d_in[0];
    const float* W     = (const float*)d_in[1];
    const float* gamma = (const float*)d_in[2];
    const float* beta  = (const float*)d_in[3];
    const int*   nump  = (const int*)d_in[4];
    const int*   coors = (const int*)d_in[5];
    float* out = (float*)d_out;

    float* wptab = (float*)d_ws;                                  // 1 KB
    float4* btab = (float4*)((char*)d_ws + 1024);                 // 2 KB
    float* scsh  = (float*)((char*)d_ws + 3072);                  // 512 B
    float* partials = (float*)((char*)d_ws + 4096);               // 1563*64*4B = 400 KB

    sap_prep<<<1, 64, 0, stream>>>(W, gamma, wptab, btab);
    sap_pass1<<<NBLK, 256, 0, stream>>>(
        (const float4*)feat, nump, (const int4*)coors, (const f2*)wptab,
        btab, out, partials);
    sap_reduce_finalize<<<1, 256, 0, stream>>>(partials, W, gamma, beta, scsh);
    sap_pass2<<<(NP * OC / 4 + 255) / 256, 256, 0, stream>>>(scsh, out);
}

// Round 15
// 60.568 us; speedup vs baseline: 2.4524x; 2.4524x over previous
//
#include <hip/hip_runtime.h>
#include <stdint.h>

#define NP 100000
#define MP 32
#define OC 64
#define NBLK 1563                 // ceil(NP/64): one 64-pillar group per block
#define BNEPS 0.001f
#define MTOT 3200000.0
#define GIDX(i,j) ((i)*10 - (i)*((i)-1)/2 + ((j)-(i)))   // 10x10 upper-tri, 55
#define BG(a,b) B[((a)<=(b)) ? ((a)*(7-(a))/2+(b)) : ((b)*(7-(b))/2+(a))]  // 4x4 upper-tri, 10

typedef float f2 __attribute__((ext_vector_type(2)));

// ---- 64-lane sum (DPP butterfly + swizzle + half exchange) ----
__device__ __forceinline__ float redall(float v) {
    v += __int_as_float(__builtin_amdgcn_update_dpp(0, __float_as_int(v), 0xB1,  0xF, 0xF, true));
    v += __int_as_float(__builtin_amdgcn_update_dpp(0, __float_as_int(v), 0x4E,  0xF, 0xF, true));
    v += __int_as_float(__builtin_amdgcn_update_dpp(0, __float_as_int(v), 0x141, 0xF, 0xF, true));
    v += __int_as_float(__builtin_amdgcn_update_dpp(0, __float_as_int(v), 0x140, 0xF, 0xF, true));
    v += __int_as_float(__builtin_amdgcn_ds_swizzle(__float_as_int(v), 0x401F));
    v += __shfl_xor(v, 32, 64);
    return v;
}

// ---------------------------------------------------------------------------
// Prep: folded weights. wptab[(c/2)*4+k] = f2{sgn*w2[k]}(ch c even/odd halves);
// btab[2c]={sgn*wcl[0..2], sgn*wce[0]}, btab[2c+1]={sgn*wce[1..2], sgn, 0}.
// ---------------------------------------------------------------------------
__global__ void sap_prep(const float* __restrict__ W, const float* __restrict__ gamma,
                         float* __restrict__ wptab, float4* __restrict__ btab)
{
    const int c = threadIdx.x;   // 64
    float w2[4], wcl[3], wce[3];
    w2[3] = W[3 * OC + c];
    #pragma unroll
    for (int k = 0; k < 3; ++k) {
        wcl[k] = W[(4 + k) * OC + c];
        wce[k] = W[(7 + k) * OC + c];
        w2[k]  = W[k * OC + c] + wcl[k] + wce[k];
    }
    const float sgn = (gamma[c] >= 0.0f) ? 1.0f : -1.0f;
    #pragma unroll
    for (int k = 0; k < 4; ++k)
        wptab[(((c >> 1) * 4) + k) * 2 + (c & 1)] = w2[k] * sgn;   // f2 halves
    btab[2*c]   = make_float4(wcl[0]*sgn, wcl[1]*sgn, wcl[2]*sgn, wce[0]*sgn);
    btab[2*c+1] = make_float4(wce[1]*sgn, wce[2]*sgn, sgn, 0.0f);
}

// ---------------------------------------------------------------------------
// Pass 1: LANE = PILLAR (r12 body). NO ATOMICS: wave 0 writes its block's 62
// partial stats to partials[block*64+lane] (coalesced, contention-free).
// ---------------------------------------------------------------------------
__global__ __launch_bounds__(256, 4) void sap_pass1(
    const float4* __restrict__ feat4, const int* __restrict__ nump,
    const int4* __restrict__ coors4, const f2* __restrict__ wptab,
    const float4* __restrict__ btab, float* __restrict__ hsel,
    float* __restrict__ partials)
{
    const int lane = threadIdx.x & 63;
    const int swid = __builtin_amdgcn_readfirstlane(threadIdx.x >> 6);
    const int n = blockIdx.x * 64 + lane;
    const bool valid = n < NP;
    const int nn = valid ? n : NP - 1;
    const int cnt = valid ? nump[nn] : 0;          // coalesced
    const int4 cr = coors4[nn];                    // coalesced 16B
    const float cenz = ((float)cr.y + 0.5f) * 0.2f;
    const float ceny = ((float)cr.z + 0.5f) * 0.2f;
    const float cenx = ((float)cr.w + 0.5f) * 4.0f;
    const float4* __restrict__ fp = feat4 + (size_t)nn * MP;

    // wave's 16 channels = 8 f2 pairs; uniform address -> scalar loads
    f2 wA[8], wB[8], wC[8], wD[8];
    #pragma unroll
    for (int j = 0; j < 8; ++j) {
        const int base = (swid * 8 + j) * 4;
        wA[j] = wptab[base];     wB[j] = wptab[base + 1];
        wC[j] = wptab[base + 2]; wD[j] = wptab[base + 3];
    }

    f2 mac[8];
    #pragma unroll
    for (int j = 0; j < 8; ++j) mac[j] = (f2){-3.0e38f, -3.0e38f};
    float S0 = 0.f, S1 = 0.f, S2 = 0.f, S3 = 0.f;
    float B[10];
    #pragma unroll
    for (int k = 0; k < 10; ++k) B[k] = 0.f;
    const bool doB = (swid == 0);

#define POINT(FF, P) {                                                          \
    const bool act = (P) < cnt;                                                 \
    const float neg = act ? 0.0f : -3.0e38f;                                    \
    const f2 neg2 = {neg, neg};                                                 \
    const f2 fx = {(FF).x, (FF).x}, fy = {(FF).y, (FF).y};                      \
    const f2 fz = {(FF).z, (FF).z}, fw = {(FF).w, (FF).w};                      \
    _Pragma("unroll")                                                           \
    for (int j = 0; j < 8; ++j) {                                               \
        const f2 d = __builtin_elementwise_fma(fx, wA[j],                       \
                     __builtin_elementwise_fma(fy, wB[j],                       \
                     __builtin_elementwise_fma(fz, wC[j],                       \
                     __builtin_elementwise_fma(fw, wD[j], neg2))));             \
        mac[j] = __builtin_elementwise_max(mac[j], d);                          \
    }                                                                           \
    const float ax = act ? (FF).x : 0.0f, ay = act ? (FF).y : 0.0f;             \
    const float az = act ? (FF).z : 0.0f;                                       \
    S0 += ax; S1 += ay; S2 += az;                                               \
    if (doB) {                                                                  \
        const float aw = act ? (FF).w : 0.0f;                                   \
        S3 += aw;                                                               \
        B[0]=fmaf(ax,ax,B[0]); B[1]=fmaf(ax,ay,B[1]); B[2]=fmaf(ax,az,B[2]);    \
        B[3]=fmaf(ax,aw,B[3]); B[4]=fmaf(ay,ay,B[4]); B[5]=fmaf(ay,az,B[5]);    \
        B[6]=fmaf(ay,aw,B[6]); B[7]=fmaf(az,az,B[7]); B[8]=fmaf(az,aw,B[8]);    \
        B[9]=fmaf(aw,aw,B[9]);                                                  \
    } }

    {
        float4 b0 = fp[0], b1 = fp[1], b2 = fp[2], b3 = fp[3];
        #pragma unroll 1
        for (int pq = 0; pq < 8; ++pq) {
            const int pb = pq * 4;
            float4 n0 = b0, n1 = b1, n2 = b2, n3 = b3;
            if (pq < 7) { n0 = fp[pb+4]; n1 = fp[pb+5]; n2 = fp[pb+6]; n3 = fp[pb+7]; }
            POINT(b0, pb + 0) POINT(b1, pb + 1)
            POINT(b2, pb + 2) POINT(b3, pb + 3)
            b0 = n0; b1 = n1; b2 = n2; b3 = n3;
        }
    }
#undef POINT

    // ---- epilogue: bias + floor + store (16 channels, 4x float4)
    const float fcnt = (float)cnt;
    const float rc = __builtin_amdgcn_rcpf(fmaxf(fcnt, 1.0f));
    const float mx = S0 * rc, my = S1 * rc, mz = S2 * rc;
    const float fl = (cnt < MP) ? 0.0f : -3.0e38f;
    #pragma unroll
    for (int q = 0; q < 4; ++q) {
        float o[4];
        #pragma unroll
        for (int k = 0; k < 4; ++k) {
            const int cc = q * 4 + k;
            const int c = swid * 16 + cc;
            const float4 bA = btab[2 * c];       // wcl0..2, wce0  (sgn-folded)
            const float4 bB = btab[2 * c + 1];   // wce1..2, sgn, 0
            const float bias = -(mx * bA.x + my * bA.y + mz * bA.z
                               + cenz * bA.w + ceny * bB.x + cenx * bB.y);
            const float m = (cc & 1) ? mac[cc >> 1].y : mac[cc >> 1].x;
            o[k] = bB.z * fmaxf(m + bias, fl);
        }
        if (valid)
            *reinterpret_cast<float4*>(hsel + (size_t)n * OC + swid * 16 + q * 4)
                = make_float4(o[0], o[1], o[2], o[3]);
    }

    // ---- wave 0: per-pillar Gram corrections -> 62 per-block partials
    if (doB) {
        float vals[62];
        const float Sf[4] = {S0, S1, S2, S3};
        const float mu[3] = {S0 * rc, S1 * rc, S2 * rc};
        const float ce[3] = {cenz, ceny, cenx};
        #pragma unroll
        for (int i = 0; i < 4; ++i)
            #pragma unroll
            for (int j = i; j < 4; ++j)
                vals[GIDX(i, j)] = BG(i, j);
        #pragma unroll
        for (int i = 0; i < 4; ++i)
            #pragma unroll
            for (int t = 0; t < 3; ++t)
                vals[GIDX(i, 4 + t)] = BG(i, t) - mu[t] * Sf[i];
        #pragma unroll
        for (int s = 0; s < 3; ++s)
            #pragma unroll
            for (int t = s; t < 3; ++t)
                vals[GIDX(4 + s, 4 + t)] = BG(s, t) - mu[s] * Sf[t];
        #pragma unroll
        for (int i = 0; i < 4; ++i)
            #pragma unroll
            for (int t = 0; t < 3; ++t)
                vals[GIDX(i, 7 + t)] = BG(i, t) - ce[t] * Sf[i];
        #pragma unroll
        for (int s = 0; s < 3; ++s)
            #pragma unroll
            for (int t = 0; t < 3; ++t)
                vals[GIDX(4 + s, 7 + t)] = BG(s, t) - mu[s] * Sf[t];
        #pragma unroll
        for (int s = 0; s < 3; ++s)
            #pragma unroll
            for (int t = s; t < 3; ++t)
                vals[GIDX(7 + s, 7 + t)] =
                    fmaf(fcnt * ce[s], ce[t], BG(s, t) - ce[s] * Sf[t] - ce[t] * Sf[s]);
        vals[55] = S0; vals[56] = S1; vals[57] = S2; vals[58] = S3;
        vals[59] = fmaf(-fcnt, cenz, S0);
        vals[60] = fmaf(-fcnt, ceny, S1);
        vals[61] = fmaf(-fcnt, cenx, S2);

        #pragma unroll
        for (int k = 0; k < 62; ++k) vals[k] = redall(vals[k]);
        float mine = 0.0f;
        #pragma unroll
        for (int k = 0; k < 62; ++k) mine = (lane == k) ? vals[k] : mine;
        if (lane < 62)
            partials[(size_t)blockIdx.x * 64 + lane] = mine;   // coalesced store
    }
}

// ---------------------------------------------------------------------------
// Reduce stage 1: 64 blocks; block g sums rows {g, g+64, ...} of partials.
// Fixed order -> deterministic. Parallel across 64 CUs (kills the r14 serial
// 98us single-block reduce).
// ---------------------------------------------------------------------------
__global__ __launch_bounds__(256) void sap_reduce1(const float* __restrict__ partials,
                                                   float* __restrict__ partials2)
{
    __shared__ float acc[4][64];
    const int k = threadIdx.x & 63, q = threadIdx.x >> 6;
    const int g = blockIdx.x;                       // 0..63
    float s = 0.0f;
    for (int b = g + 64 * q; b < NBLK; b += 256)    // ~6 rows per thread
        s += partials[(size_t)b * 64 + k];
    acc[q][k] = s;
    __syncthreads();
    if (threadIdx.x < 64)
        partials2[(size_t)g * 64 + threadIdx.x] =
            (acc[0][threadIdx.x] + acc[1][threadIdx.x]) +
            (acc[2][threadIdx.x] + acc[3][threadIdx.x]);
}

// ---------------------------------------------------------------------------
// Reduce stage 2 + finalize: sum 64 rows of partials2 (16 loads/thread),
// then fp64 Gram quadratic form -> scsh.
// ---------------------------------------------------------------------------
__global__ void sap_finalize(const float* __restrict__ partials2,
                             const float* __restrict__ W,
                             const float* __restrict__ gamma,
                             const float* __restrict__ beta,
                             float* __restrict__ scsh)
{
    __shared__ float acc[4][64];
    __shared__ float stats[64];
    const int tid = threadIdx.x;          // 256
    const int k = tid & 63, q = tid >> 6;
    float s = 0.0f;
    #pragma unroll
    for (int i = 0; i < 16; ++i)
        s += partials2[(size_t)(q + 4 * i) * 64 + k];
    acc[q][k] = s;
    __syncthreads();
    if (tid < 64) stats[tid] = (acc[0][tid] + acc[1][tid]) + (acc[2][tid] + acc[3][tid]);
    __syncthreads();
    if (tid >= 64) return;
    const int c = tid;
    double G[55];
    #pragma unroll
    for (int kk = 0; kk < 55; ++kk) G[kk] = (double)stats[kk];
    double Sg[10];
    Sg[0] = (double)stats[55]; Sg[1] = (double)stats[56];
    Sg[2] = (double)stats[57]; Sg[3] = (double)stats[58];
    Sg[4] = 0.0; Sg[5] = 0.0; Sg[6] = 0.0;
    Sg[7] = (double)stats[59]; Sg[8] = (double)stats[60]; Sg[9] = (double)stats[61];
    double w[10];
    #pragma unroll
    for (int kk = 0; kk < 10; ++kk) w[kk] = (double)W[kk * OC + c];
    double sh = 0.0, qq = 0.0;
    #pragma unroll
    for (int kk = 0; kk < 10; ++kk) sh += Sg[kk] * w[kk];
    for (int i = 0; i < 10; ++i)
        for (int j = i; j < 10; ++j) {
            const double t = w[i] * w[j] * G[GIDX(i, j)];
            qq += (i == j) ? t : 2.0 * t;
        }
    const double mu_d = sh / MTOT;
    const double var_d = qq / MTOT - mu_d * mu_d;
    const float sc = gamma[c] * rsqrtf((float)var_d + BNEPS);
    scsh[c]      = sc;
    scsh[64 + c] = beta[c] - (float)mu_d * sc;
}

// ---------------------------------------------------------------------------
// Pass 2: in-place over d_out: out = relu(scale * hsel + shift).
// ---------------------------------------------------------------------------
__global__ __launch_bounds__(256) void sap_pass2(const float* __restrict__ scsh,
                                                 float* __restrict__ out)
{
    const int idx = blockIdx.x * 256 + threadIdx.x;
    if (idx >= (NP * OC) / 4) return;
    float4 h = reinterpret_cast<float4*>(out)[idx];
    const int ci = idx & 15;
    const float4 sc = reinterpret_cast<const float4*>(scsh)[ci];
    const float4 sh = reinterpret_cast<const float4*>(scsh + 64)[ci];
    float4 o;
    o.x = fmaxf(fmaf(h.x, sc.x, sh.x), 0.0f);
    o.y = fmaxf(fmaf(h.y, sc.y, sh.y), 0.0f);
    o.z = fmaxf(fmaf(h.z, sc.z, sh.z), 0.0f);
    o.w = fmaxf(fmaf(h.w, sc.w, sh.w), 0.0f);
    reinterpret_cast<float4*>(out)[idx] = o;
}

extern "C" void kernel_launch(void* const* d_in, const int* in_sizes, int n_in,
                              void* d_out, int out_size, void* d_ws, size_t ws_size,
                              hipStream_t stream) {
    const float* feat  = (const float*)d_in[0];
    const float* W     = (const float*)d_in[1];
    const float* gamma = (const float*)d_in[2];
    const float* beta  = (const float*)d_in[3];
    const int*   nump  = (const int*)d_in[4];
    const int*   coors = (const int*)d_in[5];
    float* out = (float*)d_out;

    float* wptab = (float*)d_ws;                                  // 1 KB
    float4* btab = (float4*)((char*)d_ws + 1024);                 // 2 KB
    float* scsh  = (float*)((char*)d_ws + 3072);                  // 512 B
    float* partials  = (float*)((char*)d_ws + 4096);              // 400 KB
    float* partials2 = (float*)((char*)d_ws + 4096 + 1563*64*4);  // 16 KB

    sap_prep<<<1, 64, 0, stream>>>(W, gamma, wptab, btab);
    sap_pass1<<<NBLK, 256, 0, stream>>>(
        (const float4*)feat, nump, (const int4*)coors, (const f2*)wptab,
        btab, out, partials);
    sap_reduce1<<<64, 256, 0, stream>>>(partials, partials2);
    sap_finalize<<<1, 256, 0, stream>>>(partials2, W, gamma, beta, scsh);
    sap_pass2<<<(NP * OC / 4 + 255) / 256, 256, 0, stream>>>(scsh, out);
}

// Round 16
// 58.654 us; speedup vs baseline: 2.5324x; 1.0326x over previous
//
#include <hip/hip_runtime.h>
#include <stdint.h>

#define NP 100000
#define MP 32
#define OC 64
#define NBLK 1563                 // ceil(NP/64): one 64-pillar group per block
#define BNEPS 0.001f
#define MTOT 3200000.0
#define GIDX(i,j) ((i)*10 - (i)*((i)-1)/2 + ((j)-(i)))   // 10x10 upper-tri, 55
#define BG(a,b) B[((a)<=(b)) ? ((a)*(7-(a))/2+(b)) : ((b)*(7-(b))/2+(a))]  // 4x4 upper-tri, 10

typedef float f2 __attribute__((ext_vector_type(2)));
typedef __attribute__((address_space(3))) uint32_t as3_u32;
typedef const __attribute__((address_space(1))) uint32_t as1_u32;

// ---- 64-lane sum (DPP butterfly + swizzle + half exchange) ----
__device__ __forceinline__ float redall(float v) {
    v += __int_as_float(__builtin_amdgcn_update_dpp(0, __float_as_int(v), 0xB1,  0xF, 0xF, true));
    v += __int_as_float(__builtin_amdgcn_update_dpp(0, __float_as_int(v), 0x4E,  0xF, 0xF, true));
    v += __int_as_float(__builtin_amdgcn_update_dpp(0, __float_as_int(v), 0x141, 0xF, 0xF, true));
    v += __int_as_float(__builtin_amdgcn_update_dpp(0, __float_as_int(v), 0x140, 0xF, 0xF, true));
    v += __int_as_float(__builtin_amdgcn_ds_swizzle(__float_as_int(v), 0x401F));
    v += __shfl_xor(v, 32, 64);
    return v;
}

// ---------------------------------------------------------------------------
// Prep: folded weights. wptab[(c/2)*4+k] = f2{sgn*w2[k]}(ch c even/odd halves);
// btab[2c]={sgn*wcl[0..2], sgn*wce[0]}, btab[2c+1]={sgn*wce[1..2], sgn, 0}.
// ---------------------------------------------------------------------------
__global__ void sap_prep(const float* __restrict__ W, const float* __restrict__ gamma,
                         float* __restrict__ wptab, float4* __restrict__ btab)
{
    const int c = threadIdx.x;   // 64
    float w2[4], wcl[3], wce[3];
    w2[3] = W[3 * OC + c];
    #pragma unroll
    for (int k = 0; k < 3; ++k) {
        wcl[k] = W[(4 + k) * OC + c];
        wce[k] = W[(7 + k) * OC + c];
        w2[k]  = W[k * OC + c] + wcl[k] + wce[k];
    }
    const float sgn = (gamma[c] >= 0.0f) ? 1.0f : -1.0f;
    #pragma unroll
    for (int k = 0; k < 4; ++k)
        wptab[(((c >> 1) * 4) + k) * 2 + (c & 1)] = w2[k] * sgn;   // f2 halves
    btab[2*c]   = make_float4(wcl[0]*sgn, wcl[1]*sgn, wcl[2]*sgn, wce[0]*sgn);
    btab[2*c+1] = make_float4(wce[1]*sgn, wce[2]*sgn, sgn, 0.0f);
}

// ---------------------------------------------------------------------------
// Pass 1: LANE = PILLAR; block stages its 64 pillars (32 KB) ONCE via
// global_load_lds (inverse-XOR-swizzled source, linear LDS dest => coalesced
// 64B-line stream, no per-wave redundancy); conflict-free swizzled
// ds_read_b128 feeds the packed-f32 channel math. NO ATOMICS: wave 0 writes
// its block's 62 partial stats to partials[block*64+lane].
// ---------------------------------------------------------------------------
__global__ __launch_bounds__(256, 4) void sap_pass1(
    const float4* __restrict__ feat4, const int* __restrict__ nump,
    const int4* __restrict__ coors4, const f2* __restrict__ wptab,
    const float4* __restrict__ btab, float* __restrict__ hsel,
    float* __restrict__ partials)
{
    __shared__ float lds[64 * MP * 4];   // 32 KB: granule g=(pillar*32+pg) at byte g*16
    const int tid  = threadIdx.x;
    const int lane = tid & 63;
    const int swid = __builtin_amdgcn_readfirstlane(tid >> 6);

    // ---- stage: LDS[pillar][pg] = feat[pillar][pg ^ (pillar&31)]
    {
        const size_t blockBase = (size_t)blockIdx.x * (64 * MP);
        #pragma unroll
        for (int it = 0; it < 8; ++it) {
            const int g = it * 256 + tid;          // granule 0..2047
            const int pil = g >> 5, pg = g & 31;
            size_t se = blockBase + (size_t)(pil * MP + (pg ^ (pil & 31)));
            if (se >= (size_t)NP * MP) se = 0;     // safe pad for last block
            __builtin_amdgcn_global_load_lds((as1_u32*)(feat4 + se),
                                             (as3_u32*)(&lds[g * 4]), 16, 0, 0);
        }
    }

    // per-lane metadata while staging is in flight
    const int n = blockIdx.x * 64 + lane;
    const bool valid = n < NP;
    const int nn = valid ? n : NP - 1;
    const int cnt = valid ? nump[nn] : 0;          // coalesced
    const int4 cr = coors4[nn];                    // coalesced 16B
    const float cenz = ((float)cr.y + 0.5f) * 0.2f;
    const float ceny = ((float)cr.z + 0.5f) * 0.2f;
    const float cenx = ((float)cr.w + 0.5f) * 4.0f;

    // wave's 16 channels = 8 f2 pairs; uniform address -> scalar loads
    f2 wA[8], wB[8], wC[8], wD[8];
    #pragma unroll
    for (int j = 0; j < 8; ++j) {
        const int base = (swid * 8 + j) * 4;
        wA[j] = wptab[base];     wB[j] = wptab[base + 1];
        wC[j] = wptab[base + 2]; wD[j] = wptab[base + 3];
    }

    f2 mac[8];
    #pragma unroll
    for (int j = 0; j < 8; ++j) mac[j] = (f2){-3.0e38f, -3.0e38f};
    float S0 = 0.f, S1 = 0.f, S2 = 0.f, S3 = 0.f;
    float B[10];
    #pragma unroll
    for (int k = 0; k < 10; ++k) B[k] = 0.f;
    const bool doB = (swid == 0);

    __syncthreads();                               // staged chunk resident

    const float4* __restrict__ lp = reinterpret_cast<const float4*>(lds);
    const int gb = lane << 5;                      // this lane's pillar base granule
    const int xm = lane & 31;                      // read-side XOR (matches source)

#define POINT(FF, P) {                                                          \
    const bool act = (P) < cnt;                                                 \
    const float neg = act ? 0.0f : -3.0e38f;                                    \
    const f2 neg2 = {neg, neg};                                                 \
    const f2 fx = {(FF).x, (FF).x}, fy = {(FF).y, (FF).y};                      \
    const f2 fz = {(FF).z, (FF).z}, fw = {(FF).w, (FF).w};                      \
    _Pragma("unroll")                                                           \
    for (int j = 0; j < 8; ++j) {                                               \
        const f2 d = __builtin_elementwise_fma(fx, wA[j],                       \
                     __builtin_elementwise_fma(fy, wB[j],                       \
                     __builtin_elementwise_fma(fz, wC[j],                       \
                     __builtin_elementwise_fma(fw, wD[j], neg2))));             \
        mac[j] = __builtin_elementwise_max(mac[j], d);                          \
    }                                                                           \
    const float ax = act ? (FF).x : 0.0f, ay = act ? (FF).y : 0.0f;             \
    const float az = act ? (FF).z : 0.0f;                                       \
    S0 += ax; S1 += ay; S2 += az;                                               \
    if (doB) {                                                                  \
        const float aw = act ? (FF).w : 0.0f;                                   \
        S3 += aw;                                                               \
        B[0]=fmaf(ax,ax,B[0]); B[1]=fmaf(ax,ay,B[1]); B[2]=fmaf(ax,az,B[2]);    \
        B[3]=fmaf(ax,aw,B[3]); B[4]=fmaf(ay,ay,B[4]); B[5]=fmaf(ay,az,B[5]);    \
        B[6]=fmaf(ay,aw,B[6]); B[7]=fmaf(az,az,B[7]); B[8]=fmaf(az,aw,B[8]);    \
        B[9]=fmaf(aw,aw,B[9]);                                                  \
    } }

    {
        #pragma unroll 1
        for (int pq = 0; pq < 8; ++pq) {
            const int pb = pq * 4;
            const float4 f0 = lp[gb + ((pb + 0) ^ xm)];
            const float4 f1 = lp[gb + ((pb + 1) ^ xm)];
            const float4 f2v = lp[gb + ((pb + 2) ^ xm)];
            const float4 f3 = lp[gb + ((pb + 3) ^ xm)];
            POINT(f0, pb + 0) POINT(f1, pb + 1)
            POINT(f2v, pb + 2) POINT(f3, pb + 3)
        }
    }
#undef POINT

    // ---- epilogue: bias + floor + store (16 channels, 4x float4)
    const float fcnt = (float)cnt;
    const float rc = __builtin_amdgcn_rcpf(fmaxf(fcnt, 1.0f));
    const float mx = S0 * rc, my = S1 * rc, mz = S2 * rc;
    const float fl = (cnt < MP) ? 0.0f : -3.0e38f;
    #pragma unroll
    for (int q = 0; q < 4; ++q) {
        float o[4];
        #pragma unroll
        for (int k = 0; k < 4; ++k) {
            const int cc = q * 4 + k;
            const int c = swid * 16 + cc;
            const float4 bA = btab[2 * c];       // wcl0..2, wce0  (sgn-folded)
            const float4 bB = btab[2 * c + 1];   // wce1..2, sgn, 0
            const float bias = -(mx * bA.x + my * bA.y + mz * bA.z
                               + cenz * bA.w + ceny * bB.x + cenx * bB.y);
            const float m = (cc & 1) ? mac[cc >> 1].y : mac[cc >> 1].x;
            o[k] = bB.z * fmaxf(m + bias, fl);
        }
        if (valid)
            *reinterpret_cast<float4*>(hsel + (size_t)n * OC + swid * 16 + q * 4)
                = make_float4(o[0], o[1], o[2], o[3]);
    }

    // ---- wave 0: per-pillar Gram corrections -> 62 per-block partials
    if (doB) {
        float vals[62];
        const float Sf[4] = {S0, S1, S2, S3};
        const float mu[3] = {S0 * rc, S1 * rc, S2 * rc};
        const float ce[3] = {cenz, ceny, cenx};
        #pragma unroll
        for (int i = 0; i < 4; ++i)
            #pragma unroll
            for (int j = i; j < 4; ++j)
                vals[GIDX(i, j)] = BG(i, j);
        #pragma unroll
        for (int i = 0; i < 4; ++i)
            #pragma unroll
            for (int t = 0; t < 3; ++t)
                vals[GIDX(i, 4 + t)] = BG(i, t) - mu[t] * Sf[i];
        #pragma unroll
        for (int s = 0; s < 3; ++s)
            #pragma unroll
            for (int t = s; t < 3; ++t)
                vals[GIDX(4 + s, 4 + t)] = BG(s, t) - mu[s] * Sf[t];
        #pragma unroll
        for (int i = 0; i < 4; ++i)
            #pragma unroll
            for (int t = 0; t < 3; ++t)
                vals[GIDX(i, 7 + t)] = BG(i, t) - ce[t] * Sf[i];
        #pragma unroll
        for (int s = 0; s < 3; ++s)
            #pragma unroll
            for (int t = 0; t < 3; ++t)
                vals[GIDX(4 + s, 7 + t)] = BG(s, t) - mu[s] * Sf[t];
        #pragma unroll
        for (int s = 0; s < 3; ++s)
            #pragma unroll
            for (int t = s; t < 3; ++t)
                vals[GIDX(7 + s, 7 + t)] =
                    fmaf(fcnt * ce[s], ce[t], BG(s, t) - ce[s] * Sf[t] - ce[t] * Sf[s]);
        vals[55] = S0; vals[56] = S1; vals[57] = S2; vals[58] = S3;
        vals[59] = fmaf(-fcnt, cenz, S0);
        vals[60] = fmaf(-fcnt, ceny, S1);
        vals[61] = fmaf(-fcnt, cenx, S2);

        #pragma unroll
        for (int k = 0; k < 62; ++k) vals[k] = redall(vals[k]);
        float mine = 0.0f;
        #pragma unroll
        for (int k = 0; k < 62; ++k) mine = (lane == k) ? vals[k] : mine;
        if (lane < 62)
            partials[(size_t)blockIdx.x * 64 + lane] = mine;   // coalesced store
    }
}

// ---------------------------------------------------------------------------
// Reduce stage 1: 64 blocks; block g sums rows {g, g+64, ...} of partials.
// ---------------------------------------------------------------------------
__global__ __launch_bounds__(256) void sap_reduce1(const float* __restrict__ partials,
                                                   float* __restrict__ partials2)
{
    __shared__ float acc[4][64];
    const int k = threadIdx.x & 63, q = threadIdx.x >> 6;
    const int g = blockIdx.x;                       // 0..63
    float s = 0.0f;
    for (int b = g + 64 * q; b < NBLK; b += 256)    // ~6 rows per thread
        s += partials[(size_t)b * 64 + k];
    acc[q][k] = s;
    __syncthreads();
    if (threadIdx.x < 64)
        partials2[(size_t)g * 64 + threadIdx.x] =
            (acc[0][threadIdx.x] + acc[1][threadIdx.x]) +
            (acc[2][threadIdx.x] + acc[3][threadIdx.x]);
}

// ---------------------------------------------------------------------------
// Reduce stage 2 + finalize: sum 64 rows of partials2, fp64 Gram -> scsh.
// ---------------------------------------------------------------------------
__global__ void sap_finalize(const float* __restrict__ partials2,
                             const float* __restrict__ W,
                             const float* __restrict__ gamma,
                             const float* __restrict__ beta,
                             float* __restrict__ scsh)
{
    __shared__ float acc[4][64];
    __shared__ float stats[64];
    const int tid = threadIdx.x;          // 256
    const int k = tid & 63, q = tid >> 6;
    float s = 0.0f;
    #pragma unroll
    for (int i = 0; i < 16; ++i)
        s += partials2[(size_t)(q + 4 * i) * 64 + k];
    acc[q][k] = s;
    __syncthreads();
    if (tid < 64) stats[tid] = (acc[0][tid] + acc[1][tid]) + (acc[2][tid] + acc[3][tid]);
    __syncthreads();
    if (tid >= 64) return;
    const int c = tid;
    double G[55];
    #pragma unroll
    for (int kk = 0; kk < 55; ++kk) G[kk] = (double)stats[kk];
    double Sg[10];
    Sg[0] = (double)stats[55]; Sg[1] = (double)stats[56];
    Sg[2] = (double)stats[57]; Sg[3] = (double)stats[58];
    Sg[4] = 0.0; Sg[5] = 0.0; Sg[6] = 0.0;
    Sg[7] = (double)stats[59]; Sg[8] = (double)stats[60]; Sg[9] = (double)stats[61];
    double w[10];
    #pragma unroll
    for (int kk = 0; kk < 10; ++kk) w[kk] = (double)W[kk * OC + c];
    double sh = 0.0, qq = 0.0;
    #pragma unroll
    for (int kk = 0; kk < 10; ++kk) sh += Sg[kk] * w[kk];
    for (int i = 0; i < 10; ++i)
        for (int j = i; j < 10; ++j) {
            const double t = w[i] * w[j] * G[GIDX(i, j)];
            qq += (i == j) ? t : 2.0 * t;
        }
    const double mu_d = sh / MTOT;
    const double var_d = qq / MTOT - mu_d * mu_d;
    const float sc = gamma[c] * rsqrtf((float)var_d + BNEPS);
    scsh[c]      = sc;
    scsh[64 + c] = beta[c] - (float)mu_d * sc;
}

// ---------------------------------------------------------------------------
// Pass 2: in-place over d_out: out = relu(scale * hsel + shift).
// ---------------------------------------------------------------------------
__global__ __launch_bounds__(256) void sap_pass2(const float* __restrict__ scsh,
                                                 float* __restrict__ out)
{
    const int idx = blockIdx.x * 256 + threadIdx.x;
    if (idx >= (NP * OC) / 4) return;
    float4 h = reinterpret_cast<float4*>(out)[idx];
    const int ci = idx & 15;
    const float4 sc = reinterpret_cast<const float4*>(scsh)[ci];
    const float4 sh = reinterpret_cast<const float4*>(scsh + 64)[ci];
    float4 o;
    o.x = fmaxf(fmaf(h.x, sc.x, sh.x), 0.0f);
    o.y = fmaxf(fmaf(h.y, sc.y, sh.y), 0.0f);
    o.z = fmaxf(fmaf(h.z, sc.z, sh.z), 0.0f);
    o.w = fmaxf(fmaf(h.w, sc.w, sh.w), 0.0f);
    reinterpret_cast<float4*>(out)[idx] = o;
}

extern "C" void kernel_launch(void* const* d_in, const int* in_sizes, int n_in,
                              void* d_out, int out_size, void* d_ws, size_t ws_size,
                              hipStream_t stream) {
    const float* feat  = (const float*)d_in[0];
    const float* W     = (const float*)d_in[1];
    const float* gamma = (const float*)d_in[2];
    const float* beta  = (const float*)d_in[3];
    const int*   nump  = (const int*)d_in[4];
    const int*   coors = (const int*)d_in[5];
    float* out = (float*)d_out;

    float* wptab = (float*)d_ws;                                  // 1 KB
    float4* btab = (float4*)((char*)d_ws + 1024);                 // 2 KB
    float* scsh  = (float*)((char*)d_ws + 3072);                  // 512 B
    float* partials  = (float*)((char*)d_ws + 4096);              // 400 KB
    float* partials2 = (float*)((char*)d_ws + 4096 + 1563*64*4);  // 16 KB

    sap_prep<<<1, 64, 0, stream>>>(W, gamma, wptab, btab);
    sap_pass1<<<NBLK, 256, 0, stream>>>(
        (const float4*)feat, nump, (const int4*)coors, (const f2*)wptab,
        btab, out, partials);
    sap_reduce1<<<64, 256, 0, stream>>>(partials, partials2);
    sap_finalize<<<1, 256, 0, stream>>>(partials2, W, gamma, beta, scsh);
    sap_pass2<<<(NP * OC / 4 + 255) / 256, 256, 0, stream>>>(scsh, out);
}